// Round 2
// baseline (580.607 us; speedup 1.0000x reference)
//
#include <hip/hip_runtime.h>

typedef _Float16 half8   __attribute__((ext_vector_type(8)));
typedef __fp16   half2_t __attribute__((ext_vector_type(2)));
typedef float    floatx4 __attribute__((ext_vector_type(4)));

// ---------------------------------------------------------------------------
// Kernel 1: sort each (n,c) 1024-vector descending, write fp16 to workspace.
// One wave (64 lanes) per vector, 16 elements/lane, register-resident bitonic:
//   - element index i = lane*16 + r
//   - j in {1..8}: in-register compare-exchange (static, fully unrolled)
//   - j >= 16:     cross-lane elementwise CE via __shfl_xor (lane dist j/16)
// ws layout: z[c][n][x], row = c*256 + n  (channel-major for GEMM staging)
// ---------------------------------------------------------------------------
__global__ __launch_bounds__(256) void sort_kernel(const float* __restrict__ x,
                                                   unsigned short* __restrict__ zs) {
  const int wave = threadIdx.x >> 6;
  const int lane = threadIdx.x & 63;
  const int vec  = (blockIdx.x << 2) + wave;     // vec = n*64 + c, 0..16383

  const float* src = x + ((size_t)vec << 10) + (lane << 4);
  float v[16];
#pragma unroll
  for (int r4 = 0; r4 < 4; ++r4) {
    float4 f = *reinterpret_cast<const float4*>(src + (r4 << 2));
    v[r4 * 4 + 0] = f.x; v[r4 * 4 + 1] = f.y;
    v[r4 * 4 + 2] = f.z; v[r4 * 4 + 3] = f.w;
  }

  // compare-exchange: desc=true -> v[a] >= v[b] afterwards
  auto CEs = [&](int a, int b, bool desc) {
    float lo = fminf(v[a], v[b]);
    float hi = fmaxf(v[a], v[b]);
    v[a] = desc ? hi : lo;
    v[b] = desc ? lo : hi;
  };

  // ---- phase A: k = 2, 4, 8 (direction static per element) ----
#pragma unroll
  for (int r = 0; r < 16; r += 2) CEs(r, r + 1, (r & 2) == 0);          // k=2  j=1
#pragma unroll
  for (int r = 0; r < 16; ++r) if ((r & 2) == 0) CEs(r, r | 2, (r & 4) == 0); // k=4 j=2
#pragma unroll
  for (int r = 0; r < 16; r += 2) CEs(r, r + 1, (r & 4) == 0);          // k=4  j=1
#pragma unroll
  for (int r = 0; r < 16; ++r) if ((r & 4) == 0) CEs(r, r | 4, (r & 8) == 0); // k=8 j=4
#pragma unroll
  for (int r = 0; r < 16; ++r) if ((r & 2) == 0) CEs(r, r | 2, (r & 8) == 0); // k=8 j=2
#pragma unroll
  for (int r = 0; r < 16; r += 2) CEs(r, r + 1, (r & 8) == 0);          // k=8  j=1

  // ---- main: k = 16 .. 1024, direction uniform per lane ----
#pragma unroll
  for (int k = 16; k <= 1024; k <<= 1) {
    const bool d = (lane & (k >> 4)) == 0;   // descending-run flag for this lane
#pragma unroll
    for (int j = k >> 1; j >= 16; j >>= 1) { // cross-lane stages
      const int dl = j >> 4;
      const bool keepmax = (((lane & dl) == 0) == d);
#pragma unroll
      for (int r = 0; r < 16; ++r) {
        float p = __shfl_xor(v[r], dl, 64);
        v[r] = keepmax ? fmaxf(v[r], p) : fminf(v[r], p);
      }
    }
#pragma unroll
    for (int j = 8; j >= 1; j >>= 1)         // in-lane cleanup
#pragma unroll
      for (int r = 0; r < 16; ++r)
        if ((r & j) == 0) CEs(r, r | j, d);
  }

  // ---- write fp16 (RTZ pack), channel-major layout ----
  const int n = vec >> 6, c = vec & 63;
  union { half2_t h2[8]; uint4 u[2]; } pk;
#pragma unroll
  for (int r = 0; r < 8; ++r)
    pk.h2[r] = __builtin_amdgcn_cvt_pkrtz(v[2 * r], v[2 * r + 1]);
  uint4* dst = reinterpret_cast<uint4*>(zs + ((size_t)(c * 256 + n) << 10) + (lane << 4));
  dst[0] = pk.u[0];
  dst[1] = pk.u[1];
}

// ---------------------------------------------------------------------------
// Kernel 2: per-channel GEMM  Y_c = Z_c (256x1024 fp16) * W_c^T (1024x1024 f32)
// + bias + sigmoid.  128x128 tile, BK=32, 4 waves (2x2), each wave a 64x64
// sub-tile of 4x4 mfma_f32_16x16x32_f16.  LDS layout: row-major stride 32
// halves with XOR swizzle on 8-half (16B) chunks: chunk' = chunk ^ ((r>>1)&3)
// -> b128 frag reads are 2-way (free) instead of 8-way conflicted.
// Verified layouts: A[m=lane&15][k=quad*8+j]; B sym.; D row=(lane>>4)*4+reg,
// col=lane&15.
// grid = (16, 64): blockIdx.x = mt*8+nt so the two M-tiles of one N-slice
// land on the same XCD (W_c slice L2 reuse).
// ---------------------------------------------------------------------------
__global__ __launch_bounds__(256) void gemm_kernel(const unsigned short* __restrict__ zs,
                                                   const float* __restrict__ W,
                                                   const float* __restrict__ bias,
                                                   float* __restrict__ out) {
  __shared__ unsigned short As[128 * 32];
  __shared__ unsigned short Bs[128 * 32];

  const int c    = blockIdx.y;
  const int t    = blockIdx.x;
  const int mt   = t >> 3;                 // 0..1
  const int nt   = t & 7;                  // 0..7
  const int tid  = threadIdx.x;
  const int wave = tid >> 6, lane = tid & 63;
  const int wm   = wave & 1, wn = wave >> 1;
  const int lr   = lane & 15;              // fragment row/col within 16
  const int q    = lane >> 4;              // quad (k-chunk selector)

  const unsigned short* Zbase = zs + (((size_t)(c * 256 + mt * 128)) << 10);
  const float*          Wbase = W + ((size_t)c << 20) + ((size_t)(nt * 128) << 10);

  floatx4 acc[4][4] = {};

  for (int kb = 0; kb < 1024; kb += 32) {
    // --- stage A: fp16 z rows, 16B per id, 512 ids ---
#pragma unroll
    for (int id = tid; id < 512; id += 256) {
      const int r = id >> 2, c8 = id & 3;
      const int ck = c8 ^ ((r >> 1) & 3);
      const uint4 val =
          *reinterpret_cast<const uint4*>(Zbase + ((size_t)r << 10) + kb + (c8 << 3));
      *reinterpret_cast<uint4*>(&As[(r << 5) + (ck << 3)]) = val;
    }
    // --- stage B: fp32 W rows -> fp16, 8 floats per id ---
#pragma unroll
    for (int id = tid; id < 512; id += 256) {
      const int r = id >> 2, c8 = id & 3;
      const int ck = c8 ^ ((r >> 1) & 3);
      const float* wp = Wbase + ((size_t)r << 10) + kb + (c8 << 3);
      const float4 f0 = *reinterpret_cast<const float4*>(wp);
      const float4 f1 = *reinterpret_cast<const float4*>(wp + 4);
      union { half2_t h2[4]; uint4 u; } pk;
      pk.h2[0] = __builtin_amdgcn_cvt_pkrtz(f0.x, f0.y);
      pk.h2[1] = __builtin_amdgcn_cvt_pkrtz(f0.z, f0.w);
      pk.h2[2] = __builtin_amdgcn_cvt_pkrtz(f1.x, f1.y);
      pk.h2[3] = __builtin_amdgcn_cvt_pkrtz(f1.z, f1.w);
      *reinterpret_cast<uint4*>(&Bs[(r << 5) + (ck << 3)]) = pk.u;
    }
    __syncthreads();

    half8 af[4], bf[4];
#pragma unroll
    for (int mi = 0; mi < 4; ++mi) {
      const int r = wm * 64 + mi * 16 + lr;
      const int ck = q ^ ((r >> 1) & 3);
      af[mi] = *reinterpret_cast<const half8*>(&As[(r << 5) + (ck << 3)]);
    }
#pragma unroll
    for (int ni = 0; ni < 4; ++ni) {
      const int r = wn * 64 + ni * 16 + lr;
      const int ck = q ^ ((r >> 1) & 3);
      bf[ni] = *reinterpret_cast<const half8*>(&Bs[(r << 5) + (ck << 3)]);
    }
#pragma unroll
    for (int mi = 0; mi < 4; ++mi)
#pragma unroll
      for (int ni = 0; ni < 4; ++ni)
        acc[mi][ni] =
            __builtin_amdgcn_mfma_f32_16x16x32_f16(af[mi], bf[ni], acc[mi][ni], 0, 0, 0);
    __syncthreads();
  }

  // --- epilogue: bias + sigmoid, out[n][c][o] fp32 ---
#pragma unroll
  for (int ni = 0; ni < 4; ++ni) {
    const int col = nt * 128 + wn * 64 + ni * 16 + lr;
    const float bv = bias[(c << 10) + col];
#pragma unroll
    for (int mi = 0; mi < 4; ++mi) {
      const int row0 = mt * 128 + wm * 64 + mi * 16 + q * 4;
#pragma unroll
      for (int rr = 0; rr < 4; ++rr) {
        const float y = acc[mi][ni][rr] + bv;
        const float s = 1.0f / (1.0f + __expf(-y));
        out[((((size_t)(row0 + rr) << 6) + c) << 10) + col] = s;
      }
    }
  }
}

extern "C" void kernel_launch(void* const* d_in, const int* in_sizes, int n_in,
                              void* d_out, int out_size, void* d_ws, size_t ws_size,
                              hipStream_t stream) {
  const float* x    = (const float*)d_in[0];   // (256, 64, 32, 32) f32
  const float* W    = (const float*)d_in[1];   // (64, 1024, 1024) f32
  const float* bias = (const float*)d_in[2];   // (64, 1024) f32
  float*       out  = (float*)d_out;           // (256, 64, 1024) f32
  unsigned short* zs = (unsigned short*)d_ws;  // 16384*1024 fp16 = 33.5 MB

  sort_kernel<<<4096, 256, 0, stream>>>(x, zs);
  gemm_kernel<<<dim3(16, 64), 256, 0, stream>>>(zs, W, bias, out);
}